// Round 1
// baseline (340.820 us; speedup 1.0000x reference)
//
#include <hip/hip_runtime.h>

#define B_   2
#define H_   16
#define HK_  4
#define G_   4
#define S_   2048
#define D_   128
#define I_   2048

#define BM   128
#define BN   64
#define TPB  256   // 4 waves

#define LDK  136   // K/U LDS row stride (f16 elems): 128 + 8 pad -> 16B-aligned b128, 2-way free
#define LDV  72    // Vt row stride: 64 + 8 pad
#define LDA  40    // A-scratch row stride: 32 + 8 pad (two 32-col halves sequentially)

static constexpr float SCALE = 0.08838834764831845f;  // 1/sqrt(128)

typedef _Float16 h8v __attribute__((ext_vector_type(8)));
typedef _Float16 h4v __attribute__((ext_vector_type(4)));
typedef float    f4v __attribute__((ext_vector_type(4)));

__global__ __launch_bounds__(TPB, 2) void flashmlp_kernel(
    const float* __restrict__ Qg, const float* __restrict__ Kg,
    const float* __restrict__ Ug, const float* __restrict__ Vg,
    float* __restrict__ Og)
{
    // LDS: 2*(64*136) + 128*72 + 128*40 = 31744 f16 = 63488 B  (2 blocks/CU)
    __shared__ _Float16 Ks[BN * LDK];
    __shared__ _Float16 Us[BN * LDK];
    __shared__ _Float16 Vt[D_ * LDV];   // Vt[d][i]  (transposed V tile)
    __shared__ _Float16 As[BM * LDA];   // wave-private rows: no barriers needed around it

    // ---- block decode with XCD swizzle: xcd = bid&7 -> kv-head = xcd>>1 (2 XCDs per head,
    // ---- 3 MB K/U/V working set fits each XCD's 4 MiB L2)
    const int bid   = blockIdx.x;
    const int xcd   = bid & 7;
    const int kh    = xcd >> 1;
    const int j     = ((bid >> 3) << 1) | (xcd & 1);   // 0..127 within head
    const int stile = j & 15;
    const int bg    = j >> 4;          // 0..7
    const int b     = bg >> 2;
    const int g     = bg & 3;
    const int h     = kh * G_ + g;

    const int tid  = threadIdx.x;
    const int wave = tid >> 6;
    const int lane = tid & 63;
    const int m16  = lane & 15;
    const int qq   = lane >> 4;        // 0..3

    const size_t qbase  = ((size_t)(b * H_ + h) * S_ + (size_t)stile * BM) * D_;
    const size_t kvbase = (size_t)kh * I_ * D_;

    // ---- Q fragments (A-operand) straight from global into registers, f32 -> f16.
    // lane(m16,qq): rows are 16-consecutive, bytes [k*128 + qq*32, +32) -> wave covers
    // 16 rows x 128B contiguous per kstep: fully coalesced.
    h8v qf[2][4];
#pragma unroll
    for (int rt = 0; rt < 2; ++rt) {
        const float* qp = Qg + qbase + (size_t)(wave * 32 + rt * 16 + m16) * D_;
#pragma unroll
        for (int ks = 0; ks < 4; ++ks) {
            const float4 a = *(const float4*)(qp + ks * 32 + qq * 8);
            const float4 c = *(const float4*)(qp + ks * 32 + qq * 8 + 4);
            h8v v;
            v[0] = (_Float16)a.x; v[1] = (_Float16)a.y; v[2] = (_Float16)a.z; v[3] = (_Float16)a.w;
            v[4] = (_Float16)c.x; v[5] = (_Float16)c.y; v[6] = (_Float16)c.z; v[7] = (_Float16)c.w;
            qf[rt][ks] = v;
        }
    }

    f4v acc_o[2][8];
#pragma unroll
    for (int rt = 0; rt < 2; ++rt)
#pragma unroll
        for (int dt = 0; dt < 8; ++dt)
            acc_o[rt][dt] = f4v{0.f, 0.f, 0.f, 0.f};

    const int sr = tid >> 2;          // K/U staging row 0..63
    const int sc = (tid & 3) * 32;    // K/U staging col base

    for (int it = 0; it < I_ / BN; ++it) {
        const int i0 = it * BN;

        __syncthreads();  // previous iter's Ks/Us/Vt reads must complete before overwrite

        // ---- stage K, U (row-major, f32 -> f16), coalesced global reads
        {
            const float* kp = Kg + kvbase + (size_t)(i0 + sr) * D_ + sc;
            const float* up = Ug + kvbase + (size_t)(i0 + sr) * D_ + sc;
            h8v kb[4], ub[4];
            _Float16* kbf = (_Float16*)kb;
            _Float16* ubf = (_Float16*)ub;
#pragma unroll
            for (int g8 = 0; g8 < 8; ++g8) {
                const float4 kv = *(const float4*)(kp + g8 * 4);
                const float4 uv = *(const float4*)(up + g8 * 4);
                kbf[g8*4+0] = (_Float16)kv.x; kbf[g8*4+1] = (_Float16)kv.y;
                kbf[g8*4+2] = (_Float16)kv.z; kbf[g8*4+3] = (_Float16)kv.w;
                ubf[g8*4+0] = (_Float16)uv.x; ubf[g8*4+1] = (_Float16)uv.y;
                ubf[g8*4+2] = (_Float16)uv.z; ubf[g8*4+3] = (_Float16)uv.w;
            }
#pragma unroll
            for (int w8 = 0; w8 < 4; ++w8) {
                *(h8v*)(&Ks[sr * LDK + sc + w8 * 8]) = kb[w8];
                *(h8v*)(&Us[sr * LDK + sc + w8 * 8]) = ub[w8];
            }
        }
        // ---- stage V transposed: thread handles (d, i-quad); global reads coalesced along d
        {
#pragma unroll
            for (int p = 0; p < 8; ++p) {
                const int idx = p * TPB + tid;
                const int d   = idx & 127;
                const int iq  = idx >> 7;   // 0..15
                const float* vp = Vg + kvbase + (size_t)(i0 + iq * 4) * D_ + d;
                h4v w;
                w[0] = (_Float16)vp[0];
                w[1] = (_Float16)vp[D_];
                w[2] = (_Float16)vp[2 * D_];
                w[3] = (_Float16)vp[3 * D_];
                *(h4v*)(&Vt[d * LDV + iq * 4]) = w;
            }
        }
        __syncthreads();

        // ---- M = Q K^T, N = Q U^T  (per wave: 32 rows x 64 cols)
        f4v am[2][4], an[2][4];
#pragma unroll
        for (int rt = 0; rt < 2; ++rt)
#pragma unroll
            for (int ct = 0; ct < 4; ++ct) {
                am[rt][ct] = f4v{0.f, 0.f, 0.f, 0.f};
                an[rt][ct] = f4v{0.f, 0.f, 0.f, 0.f};
            }
#pragma unroll
        for (int ct = 0; ct < 4; ++ct) {
#pragma unroll
            for (int ks = 0; ks < 4; ++ks) {
                const h8v kf = *(const h8v*)(&Ks[(ct * 16 + m16) * LDK + ks * 32 + qq * 8]);
                const h8v uf = *(const h8v*)(&Us[(ct * 16 + m16) * LDK + ks * 32 + qq * 8]);
#pragma unroll
                for (int rt = 0; rt < 2; ++rt) {
                    am[rt][ct] = __builtin_amdgcn_mfma_f32_16x16x32_f16(qf[rt][ks], kf, am[rt][ct], 0, 0, 0);
                    an[rt][ct] = __builtin_amdgcn_mfma_f32_16x16x32_f16(qf[rt][ks], uf, an[rt][ct], 0, 0, 0);
                }
            }
        }

        // ---- gate: A = silu(M*s) * (N*s), fp32 math, -> f16
        _Float16 ag[2][4][4];
#pragma unroll
        for (int rt = 0; rt < 2; ++rt)
#pragma unroll
            for (int ct = 0; ct < 4; ++ct)
#pragma unroll
                for (int r = 0; r < 4; ++r) {
                    const float mv = am[rt][ct][r] * SCALE;
                    const float nv = an[rt][ct][r] * SCALE;
                    const float sg = 1.f / (1.f + __expf(-mv));
                    ag[rt][ct][r] = (_Float16)(mv * sg * nv);
                }

        // ---- O += A V, two 32-col halves through wave-private As (no barriers:
        // each wave writes & reads only rows [wave*32, wave*32+32))
#pragma unroll
        for (int hh = 0; hh < 2; ++hh) {
#pragma unroll
            for (int c2 = 0; c2 < 2; ++c2) {
                const int ct = hh * 2 + c2;
#pragma unroll
                for (int rt = 0; rt < 2; ++rt)
#pragma unroll
                    for (int r = 0; r < 4; ++r)
                        As[(wave * 32 + rt * 16 + qq * 4 + r) * LDA + c2 * 16 + m16] = ag[rt][ct][r];
            }
#pragma unroll
            for (int rt = 0; rt < 2; ++rt) {
                const h8v af = *(const h8v*)(&As[(wave * 32 + rt * 16 + m16) * LDA + qq * 8]);
#pragma unroll
                for (int dt = 0; dt < 8; ++dt) {
                    const h8v vf = *(const h8v*)(&Vt[(dt * 16 + m16) * LDV + hh * 32 + qq * 8]);
                    acc_o[rt][dt] = __builtin_amdgcn_mfma_f32_16x16x32_f16(af, vf, acc_o[rt][dt], 0, 0, 0);
                }
            }
        }
    }

    // ---- epilogue: C-layout -> global fp32, 16 lanes write 64B runs per row
#pragma unroll
    for (int rt = 0; rt < 2; ++rt) {
#pragma unroll
        for (int r = 0; r < 4; ++r) {
            const int row = stile * BM + wave * 32 + rt * 16 + qq * 4 + r;
            float* op = Og + ((size_t)(b * H_ + h) * S_ + row) * D_;
#pragma unroll
            for (int dt = 0; dt < 8; ++dt)
                op[dt * 16 + m16] = acc_o[rt][dt][r];
        }
    }
}

extern "C" void kernel_launch(void* const* d_in, const int* in_sizes, int n_in,
                              void* d_out, int out_size, void* d_ws, size_t ws_size,
                              hipStream_t stream) {
    const float* Q = (const float*)d_in[0];
    const float* K = (const float*)d_in[1];
    const float* U = (const float*)d_in[2];
    const float* V = (const float*)d_in[3];
    float* out = (float*)d_out;

    const int grid = (S_ / BM) * B_ * H_;   // 16 * 32 = 512 blocks, all co-resident at 2/CU
    flashmlp_kernel<<<dim3(grid), dim3(TPB), 0, stream>>>(Q, K, U, V, out);
}